// Round 8
// baseline (598.221 us; speedup 1.0000x reference)
//
#include <hip/hip_runtime.h>

// TurboFlashAttention: causal B=2,H=16,S=2048,D=64 fp32 + 512MB zero placeholder.
// R13: restructure compute to cut barrier-phase count ~2x. Ledger (R5-R12):
// fill ~85us is scheduling-invariant (5 mechanisms tried); compute wall ~150us
// = 34 slots/CU x ~10k cyc, vs ~1.5k cyc issue work/slot -> phase-overhead/
// latency-chain dominated. So: 256-row q-supertiles, 8 waves/block, KVBLK=128,
// 1 block/CU (LDS 141KiB), dbuf. Per-wave per-phase structure identical to the
// old slot (2 frags x 32 q-rows), but worst-CU phases drop 34 -> 16; the
// per-phase fixed costs (barrier, softmax shfl chains ~120cyc each) amortize
// over 2x work. Same 2 waves/SIMD. MFMA count unchanged. Diagonal now spans 2
// tiles (mask when j>=2t, qml shifted by 128(j-2t); fully-masked frags yield
// P=0/alpha=1 -> correct). Imbalance absorbed by R5-proven inverse-quadratic
// tail fill (rank r=7-t). Keeps: raw lgkm barrier, setprio, V^T swizzle.

typedef __bf16 bf16x8 __attribute__((ext_vector_type(8)));
typedef float f32x4 __attribute__((ext_vector_type(4)));

#define LOG2E 1.44269504088896340736f

__device__ __forceinline__ unsigned short f2bf(float f) {
  unsigned int u = __float_as_uint(f);
  u += 0x7fffu + ((u >> 16) & 1u);   // RNE
  return (unsigned short)(u >> 16);
}

// Cross-wave LDS sync WITHOUT the vmcnt(0) drain __syncthreads would emit.
__device__ __forceinline__ void block_sync_lds() {
  asm volatile("s_waitcnt lgkmcnt(0)" ::: "memory");
  __builtin_amdgcn_s_barrier();
}

constexpr int Sdim = 2048, Ddim = 64, BHn = 32;
constexpr int QTiles = 8;                    // 256-row q-supertiles
constexpr int LDK = 72;                      // Klds leading-dim pad (shorts)
constexpr int LDV = 136;                     // Vlds^T leading-dim pad (shorts)
constexpr int LDP = 136;                     // Plds leading-dim pad (shorts)
constexpr int OUT0 = BHn * Sdim * Ddim;      // output-region floats
constexpr size_t FILL_PER_BH = 1048576;      // f32x4 per bh (16 MiB)
constexpr int FILL_UNIT_F4 = 16384;          // 0.25 MiB unit

__device__ __forceinline__ int vswz_m(int d) { return ((d >> 2) ^ (d >> 5)) & 7; }

__global__ __launch_bounds__(512, 2)
void flash_causal_kernel(const float* __restrict__ Q, const float* __restrict__ K,
                         const float* __restrict__ V, float* __restrict__ out) {
  __shared__ unsigned short Klds[2][128 * LDK];     // K tile [kn][d]      36,864 B
  __shared__ unsigned short Vlds[2][64 * LDV];      // V^T tile [d][kn^swz] 34,816 B
  __shared__ unsigned short Plds[8][2][16 * LDP];   // per-wave P^T         69,632 B

  const int tid  = threadIdx.x;
  const int wave = tid >> 6;
  const int lane = tid & 63;
  const int quad = lane >> 4;
  const int l15  = lane & 15;

  const int bh = (int)blockIdx.x & (BHn - 1);
  const int t  = (int)blockIdx.x >> 5;         // 0..7, q-rows [256t, 256t+256)
  const int jmax = 2 * t + 1;                  // KV tiles of 128: count = 2t+2

  const int base  = bh * Sdim * Ddim;
  const int qbase = t * 256;

  // ---- Q fragments (B-operand), scale 1/8 folded. frag f: rows qbase+32w+16f.
  bf16x8 aq[2][2];
  #pragma unroll
  for (int f = 0; f < 2; ++f) {
    const float* qp = Q + base + (qbase + 32 * wave + 16 * f + l15) * Ddim + quad * 8;
    #pragma unroll
    for (int s2 = 0; s2 < 2; ++s2) {
      float4 a = *(const float4*)(qp + 32 * s2);
      float4 bq = *(const float4*)(qp + 32 * s2 + 4);
      union { unsigned short u[8]; bf16x8 v; } u;
      u.u[0] = f2bf(a.x * 0.125f);  u.u[1] = f2bf(a.y * 0.125f);
      u.u[2] = f2bf(a.z * 0.125f);  u.u[3] = f2bf(a.w * 0.125f);
      u.u[4] = f2bf(bq.x * 0.125f); u.u[5] = f2bf(bq.y * 0.125f);
      u.u[6] = f2bf(bq.z * 0.125f); u.u[7] = f2bf(bq.w * 0.125f);
      aq[f][s2] = u.v;
    }
  }

  f32x4 ot[2][4];
  #pragma unroll
  for (int f = 0; f < 2; ++f)
    #pragma unroll
    for (int tt = 0; tt < 4; ++tt) ot[f][tt] = (f32x4){0.f, 0.f, 0.f, 0.f};
  float mrun[2] = {-__builtin_inff(), -__builtin_inff()};
  float lrun[2] = {0.f, 0.f};

  const float4* kg4 = (const float4*)(K + base);
  const float4* vg4 = (const float4*)(V + base);
  float4 kf[4], vf[4];

  // tile j = kv rows [128j, 128j+128): 2048 float4, 4 per thread (512 thr).
  auto ldtile = [&](int j) {
    const float4* kp = kg4 + j * 2048;
    const float4* vp = vg4 + j * 2048;
    #pragma unroll
    for (int i = 0; i < 4; ++i) { kf[i] = kp[i * 512 + tid]; vf[i] = vp[i * 512 + tid]; }
  };
  auto stage = [&](int buf) {
    #pragma unroll
    for (int i = 0; i < 4; ++i) {
      int lin = i * 512 + tid;
      int row = lin >> 4;              // kn 0..127
      int c4  = (lin & 15) << 2;       // d 0..60
      uint2 t2;
      t2.x = (unsigned int)f2bf(kf[i].x) | ((unsigned int)f2bf(kf[i].y) << 16);
      t2.y = (unsigned int)f2bf(kf[i].z) | ((unsigned int)f2bf(kf[i].w) << 16);
      *(uint2*)&Klds[buf][row * LDK + c4] = t2;
      const int sw = vswz_m(c4) << 3;  // vswz_m constant over c4..c4+3
      Vlds[buf][(c4 + 0) * LDV + (row ^ sw)] = f2bf(vf[i].x);
      Vlds[buf][(c4 + 1) * LDV + (row ^ sw)] = f2bf(vf[i].y);
      Vlds[buf][(c4 + 2) * LDV + (row ^ sw)] = f2bf(vf[i].z);
      Vlds[buf][(c4 + 3) * LDV + (row ^ sw)] = f2bf(vf[i].w);
    }
  };

  // ---- prologue (jmax >= 1 always)
  ldtile(0); stage(0); ldtile(1);

  for (int j = 0; j <= jmax; ++j) {
    block_sync_lds();
    if (j < jmax) stage((j + 1) & 1);
    if (j + 2 <= jmax) ldtile(j + 2);

    const unsigned short* Kb = Klds[j & 1];
    const unsigned short* Vb = Vlds[j & 1];

    // ---- S^T for both frags; K fragment read once, used twice
    f32x4 sc[2][8];
    #pragma unroll
    for (int f = 0; f < 2; ++f)
      #pragma unroll
      for (int tt = 0; tt < 8; ++tt) sc[f][tt] = (f32x4){0.f, 0.f, 0.f, 0.f};
    __builtin_amdgcn_s_setprio(1);
    #pragma unroll
    for (int s2 = 0; s2 < 2; ++s2) {
      #pragma unroll
      for (int tt = 0; tt < 8; ++tt) {
        bf16x8 ka = *(const bf16x8*)&Kb[(16 * tt + l15) * LDK + 32 * s2 + quad * 8];
        sc[0][tt] = __builtin_amdgcn_mfma_f32_16x16x32_bf16(ka, aq[0][s2], sc[0][tt], 0, 0, 0);
        sc[1][tt] = __builtin_amdgcn_mfma_f32_16x16x32_bf16(ka, aq[1][s2], sc[1][tt], 0, 0, 0);
      }
    }
    __builtin_amdgcn_s_setprio(0);

    // ---- causal mask: diagonal spans tiles j=2t (partial) and j=2t+1.
    // qml = local q-row - 128*(j-2t); kn_local > qml -> -inf (qml<0: full mask,
    // degrades to P=0, alpha=1 in softmax below).
    if (j >= 2 * t) {
      #pragma unroll
      for (int f = 0; f < 2; ++f) {
        const int qml = 32 * wave + 16 * f + l15 - ((j - 2 * t) << 7);
        #pragma unroll
        for (int tt = 0; tt < 8; ++tt)
          #pragma unroll
          for (int r = 0; r < 4; ++r)
            if (16 * tt + 4 * quad + r > qml) sc[f][tt][r] = -__builtin_inff();
      }
    }

    // ---- online softmax + P write (per frag)
    #pragma unroll
    for (int f = 0; f < 2; ++f) {
      float mx = sc[f][0][0];
      #pragma unroll
      for (int tt = 0; tt < 8; ++tt)
        #pragma unroll
        for (int r = 0; r < 4; ++r) mx = fmaxf(mx, sc[f][tt][r]);
      mx = fmaxf(mx, __shfl_xor(mx, 16));
      mx = fmaxf(mx, __shfl_xor(mx, 32));
      float mn    = fmaxf(mrun[f], mx);
      float alpha = __builtin_amdgcn_exp2f((mrun[f] - mn) * LOG2E);
      float msc   = mn * LOG2E;
      mrun[f] = mn;
      float rs = 0.f;
      #pragma unroll
      for (int tt = 0; tt < 8; ++tt)
        #pragma unroll
        for (int r = 0; r < 4; ++r) {
          float p = __builtin_amdgcn_exp2f(fmaf(sc[f][tt][r], LOG2E, -msc));
          sc[f][tt][r] = p;
          rs += p;
        }
      rs += __shfl_xor(rs, 16);
      rs += __shfl_xor(rs, 32);
      lrun[f] = lrun[f] * alpha + rs;
      #pragma unroll
      for (int tt = 0; tt < 4; ++tt)
        #pragma unroll
        for (int r = 0; r < 4; ++r) ot[f][tt][r] *= alpha;
      #pragma unroll
      for (int tt = 0; tt < 8; ++tt) {
        uint2 pw;
        pw.x = (unsigned int)f2bf(sc[f][tt][0]) | ((unsigned int)f2bf(sc[f][tt][1]) << 16);
        pw.y = (unsigned int)f2bf(sc[f][tt][2]) | ((unsigned int)f2bf(sc[f][tt][3]) << 16);
        *(uint2*)&Plds[wave][f][l15 * LDP + 16 * tt + 4 * quad] = pw;
      }
    }

    // ---- O^T += V^T * P^T; V fragment read once, used for both frags
    __builtin_amdgcn_s_setprio(1);
    #pragma unroll
    for (int ks = 0; ks < 4; ++ks) {
      bf16x8 pb0 = *(const bf16x8*)&Plds[wave][0][l15 * LDP + 32 * ks + quad * 8];
      bf16x8 pb1 = *(const bf16x8*)&Plds[wave][1][l15 * LDP + 32 * ks + quad * 8];
      #pragma unroll
      for (int tt = 0; tt < 4; ++tt) {
        const int d = 16 * tt + l15;
        bf16x8 va = *(const bf16x8*)&Vb[d * LDV + (((4 * ks + quad) ^ vswz_m(d)) << 3)];
        ot[0][tt] = __builtin_amdgcn_mfma_f32_16x16x32_bf16(va, pb0, ot[0][tt], 0, 0, 0);
        ot[1][tt] = __builtin_amdgcn_mfma_f32_16x16x32_bf16(va, pb1, ot[1][tt], 0, 0, 0);
      }
    }
    __builtin_amdgcn_s_setprio(0);
  }

  // ---- epilogue
  #pragma unroll
  for (int f = 0; f < 2; ++f) {
    float inv = 1.0f / lrun[f];
    float* orow = out + base + (qbase + 32 * wave + 16 * f + l15) * Ddim + 4 * quad;
    #pragma unroll
    for (int tt = 0; tt < 4; ++tt) {
      f32x4 o4;
      o4.x = ot[f][tt][0] * inv; o4.y = ot[f][tt][1] * inv;
      o4.z = ot[f][tt][2] * inv; o4.w = ot[f][tt][3] * inv;
      *(f32x4*)(orow + 16 * tt) = o4;
    }
  }

  // ---- zero-fill placeholder, inverse-balanced (rank r=7-t; t=7 fills least).
  {
    const int r = (QTiles - 1) - t;
    const size_t start_f4 = (size_t)bh * FILL_PER_BH + (size_t)FILL_UNIT_F4 * (r * r);
    const size_t count_f4 = (size_t)FILL_UNIT_F4 * (2 * r + 1);
    f32x4 z4 = (f32x4){0.f, 0.f, 0.f, 0.f};
    f32x4* zp = (f32x4*)(out + OUT0) + start_f4;
    for (size_t i = tid; i < count_f4; i += 512)
      __builtin_nontemporal_store(z4, zp + i);
  }
}

extern "C" void kernel_launch(void* const* d_in, const int* in_sizes, int n_in,
                              void* d_out, int out_size, void* d_ws, size_t ws_size,
                              hipStream_t stream) {
  const float* q = (const float*)d_in[0];
  const float* k = (const float*)d_in[1];
  const float* v = (const float*)d_in[2];
  float* out = (float*)d_out;
  // 256 blocks x 512 threads: 32 bh x 8 supertiles, 1 block/CU (141KiB LDS),
  // all co-resident; worst block = 16 phases (vs 34 slots before).
  dim3 grid(BHn * QTiles);
  flash_causal_kernel<<<grid, dim3(512), 0, stream>>>(q, k, v, out);
}

// Round 10
// 585.400 us; speedup vs baseline: 1.0219x; 1.0219x over previous
//
#include <hip/hip_runtime.h>

// TurboFlashAttention: causal B=2,H=16,S=2048,D=64 fp32 + 512MB zero placeholder.
// R15 = R14 with the permlane register-coalescing bug fixed. R14 failed
// (absmax 2.03) because a=x,b=x got coalesced into ONE VGPR: the emitted
// v_permlane16_swap_b32 v5,v5 self-swap permutes rows but exchanges nothing,
// so fmax(a,b) returned permuted-x, not a reduction -> wrong softmax max/sum,
// O(1) errors (matches failure signature; vrow mapping re-derived consistent).
// Fix: opaque empty asm on b before each swap forces distinct VGPRs (two
// distinct live values cannot share a register at the swap instruction).
// R14 content kept: (1) softmax cross-lane reduce via v_permlane16/32_swap
// (VALU ~5cyc) replacing __shfl_xor->ds_bpermute (~120cyc x8 serial/slot),
// in-lane chains tree-ified; (2) V^T staging physical-row XOR perm vrow(d)
// spreads the 16-way ds_write_b16 bank conflict to ~4-way.
// Base: R10 (interleave s-map, raw lgkm barrier, setprio, dbuf, tail fill).

typedef __bf16 bf16x8 __attribute__((ext_vector_type(8)));
typedef float f32x4 __attribute__((ext_vector_type(4)));

#define LOG2E 1.44269504088896340736f

__device__ __forceinline__ unsigned short f2bf(float f) {
  unsigned int u = __float_as_uint(f);
  u += 0x7fffu + ((u >> 16) & 1u);   // RNE
  return (unsigned short)(u >> 16);
}

// Cross-wave LDS sync WITHOUT the vmcnt(0) drain __syncthreads would emit.
__device__ __forceinline__ void block_sync_lds() {
  asm volatile("s_waitcnt lgkmcnt(0)" ::: "memory");
  __builtin_amdgcn_s_barrier();
}

// xor-16 / xor-32 butterfly reduce at VALU speed (gfx950 permlane*_swap).
// a=b=x, swap exchanges complementary 16/32-lane rows between the two regs;
// fmax/add(a,b) is then the butterfly stage. The empty asm on b forces a
// DISTINCT VGPR (R14 bug: identical values coalesced -> self-swap -> no-op).
__device__ __forceinline__ float redmax_q(float x) {
  float a = x, b = x;
  asm volatile("" : "+v"(b));
  asm("v_permlane16_swap_b32 %0, %1" : "+v"(a), "+v"(b));
  float m = fmaxf(a, b);
  float c = m, d = m;
  asm volatile("" : "+v"(d));
  asm("v_permlane32_swap_b32 %0, %1" : "+v"(c), "+v"(d));
  return fmaxf(c, d);
}
__device__ __forceinline__ float redsum_q(float x) {
  float a = x, b = x;
  asm volatile("" : "+v"(b));
  asm("v_permlane16_swap_b32 %0, %1" : "+v"(a), "+v"(b));
  float s = a + b;
  float c = s, d = s;
  asm volatile("" : "+v"(d));
  asm("v_permlane32_swap_b32 %0, %1" : "+v"(c), "+v"(d));
  return c + d;
}

constexpr int Sdim = 2048, Ddim = 64, BHn = 32;
constexpr int STiles = 16;                   // 128-row q-supertiles
constexpr int LDK = 72;                      // LDS leading-dim pad (shorts)
constexpr int OUT0 = BHn * Sdim * Ddim;      // output-region floats
constexpr size_t FILL_PER_BH = 1048576;      // f32x4 per bh in placeholder

__device__ __forceinline__ int vswz_m(int d) { return ((d >> 2) ^ (d >> 5)) & 7; }
// physical V^T row permutation: bijective within each 8-row block; spreads
// the d-major b16 write pattern from 2 bank positions to 8 (16-way -> 4-way).
__device__ __forceinline__ int vrow(int d) { return (d & 56) | ((d ^ (d >> 3)) & 7); }

__global__ __launch_bounds__(256, 2)
void flash_causal_kernel(const float* __restrict__ Q, const float* __restrict__ K,
                         const float* __restrict__ V, float* __restrict__ out) {
  __shared__ unsigned short Klds[2][64 * LDK];      // K tile [kn][d]
  __shared__ unsigned short Vlds[2][64 * LDK];      // V^T tile [vrow(d)][kn^swz]
  __shared__ unsigned short Plds[4][2][16 * LDK];   // per-wave, per-frag P^T

  const int tid  = threadIdx.x;
  const int wave = tid >> 6;
  const int lane = tid & 63;
  const int quad = lane >> 4;
  const int l15  = lane & 15;

  const int bh = blockIdx.x & (BHn - 1);
  const int g  = (int)(blockIdx.x >> 5);                        // 0..15
  const int s  = (g & 1) ? (STiles - 1) - (g >> 1) : (g >> 1);  // interleave
  const int jmax = 2 * s + 1;

  const int base  = bh * Sdim * Ddim;
  const int qbase = s * 128;

  // ---- Q fragments (B-operand), scale 1/8 folded. frag f: rows qbase+64f+16w.
  bf16x8 aq[2][2];
  #pragma unroll
  for (int f = 0; f < 2; ++f) {
    const float* qp = Q + base + (qbase + 64 * f + wave * 16 + l15) * Ddim + quad * 8;
    #pragma unroll
    for (int s2 = 0; s2 < 2; ++s2) {
      float4 a = *(const float4*)(qp + 32 * s2);
      float4 b = *(const float4*)(qp + 32 * s2 + 4);
      union { unsigned short u[8]; bf16x8 v; } u;
      u.u[0] = f2bf(a.x * 0.125f); u.u[1] = f2bf(a.y * 0.125f);
      u.u[2] = f2bf(a.z * 0.125f); u.u[3] = f2bf(a.w * 0.125f);
      u.u[4] = f2bf(b.x * 0.125f); u.u[5] = f2bf(b.y * 0.125f);
      u.u[6] = f2bf(b.z * 0.125f); u.u[7] = f2bf(b.w * 0.125f);
      aq[f][s2] = u.v;
    }
  }

  f32x4 ot[2][4];
  #pragma unroll
  for (int f = 0; f < 2; ++f)
    #pragma unroll
    for (int t = 0; t < 4; ++t) ot[f][t] = (f32x4){0.f, 0.f, 0.f, 0.f};
  float mrun[2] = {-__builtin_inff(), -__builtin_inff()};
  float lrun[2] = {0.f, 0.f};

  const float4* kg4 = (const float4*)(K + base);
  const float4* vg4 = (const float4*)(V + base);
  float4 kf[4], vf[4];

  auto ldtile = [&](int j) {
    const float4* kp = kg4 + j * 1024;
    const float4* vp = vg4 + j * 1024;
    #pragma unroll
    for (int i = 0; i < 4; ++i) { kf[i] = kp[i * 256 + tid]; vf[i] = vp[i * 256 + tid]; }
  };
  auto stage = [&](int buf) {
    #pragma unroll
    for (int i = 0; i < 4; ++i) {
      int lin = i * 256 + tid;
      int row = lin >> 4;
      int c4  = (lin & 15) << 2;
      uint2 t2;
      t2.x = (unsigned int)f2bf(kf[i].x) | ((unsigned int)f2bf(kf[i].y) << 16);
      t2.y = (unsigned int)f2bf(kf[i].z) | ((unsigned int)f2bf(kf[i].w) << 16);
      *(uint2*)&Klds[buf][row * LDK + c4] = t2;
      const int sw = vswz_m(c4) << 3;   // vswz_m constant over c4..c4+3
      Vlds[buf][vrow(c4 + 0) * LDK + (row ^ sw)] = f2bf(vf[i].x);
      Vlds[buf][vrow(c4 + 1) * LDK + (row ^ sw)] = f2bf(vf[i].y);
      Vlds[buf][vrow(c4 + 2) * LDK + (row ^ sw)] = f2bf(vf[i].z);
      Vlds[buf][vrow(c4 + 3) * LDK + (row ^ sw)] = f2bf(vf[i].w);
    }
  };

  // ---- prologue
  ldtile(0); stage(0); ldtile(1);   // jmax >= 1 always

  for (int j = 0; j <= jmax; ++j) {
    block_sync_lds();
    if (j < jmax) stage((j + 1) & 1);
    if (j + 2 <= jmax) ldtile(j + 2);

    const unsigned short* Kb = Klds[j & 1];
    const unsigned short* Vb = Vlds[j & 1];
    const bool f0act = (j <= 2 * s);   // frag0 has no columns at j == jmax

    // ---- S^T for both frags; K fragment read once, used twice
    f32x4 sc[2][4];
    #pragma unroll
    for (int f = 0; f < 2; ++f)
      #pragma unroll
      for (int t = 0; t < 4; ++t) sc[f][t] = (f32x4){0.f, 0.f, 0.f, 0.f};
    __builtin_amdgcn_s_setprio(1);
    #pragma unroll
    for (int s2 = 0; s2 < 2; ++s2) {
      #pragma unroll
      for (int t = 0; t < 4; ++t) {
        bf16x8 ka = *(const bf16x8*)&Kb[(16 * t + l15) * LDK + 32 * s2 + quad * 8];
        sc[0][t] = __builtin_amdgcn_mfma_f32_16x16x32_bf16(ka, aq[0][s2], sc[0][t], 0, 0, 0);
        sc[1][t] = __builtin_amdgcn_mfma_f32_16x16x32_bf16(ka, aq[1][s2], sc[1][t], 0, 0, 0);
      }
    }
    __builtin_amdgcn_s_setprio(0);

    // ---- causal diagonal masks (frag f diag at j == 2s+f; local coords equal)
    #pragma unroll
    for (int f = 0; f < 2; ++f) {
      if (j == 2 * s + f) {
        const int qml = wave * 16 + l15;
        #pragma unroll
        for (int t = 0; t < 4; ++t)
          #pragma unroll
          for (int r = 0; r < 4; ++r)
            if (16 * t + 4 * quad + r > qml) sc[f][t][r] = -__builtin_inff();
      }
    }

    // ---- online softmax + P write (per frag; frag0 skipped on final odd iter)
    #pragma unroll
    for (int f = 0; f < 2; ++f) {
      if (f == 0 && !f0act) continue;
      // tree-reduce local max (depth 4), then VALU butterfly across quads
      float tmx[4];
      #pragma unroll
      for (int t = 0; t < 4; ++t)
        tmx[t] = fmaxf(fmaxf(sc[f][t][0], sc[f][t][1]),
                       fmaxf(sc[f][t][2], sc[f][t][3]));
      float mx = fmaxf(fmaxf(tmx[0], tmx[1]), fmaxf(tmx[2], tmx[3]));
      mx = redmax_q(mx);
      float mn    = fmaxf(mrun[f], mx);
      float alpha = __builtin_amdgcn_exp2f((mrun[f] - mn) * LOG2E);
      float msc   = mn * LOG2E;
      mrun[f] = mn;
      float rsp[4];
      #pragma unroll
      for (int t = 0; t < 4; ++t) {
        float p0 = __builtin_amdgcn_exp2f(fmaf(sc[f][t][0], LOG2E, -msc));
        float p1 = __builtin_amdgcn_exp2f(fmaf(sc[f][t][1], LOG2E, -msc));
        float p2 = __builtin_amdgcn_exp2f(fmaf(sc[f][t][2], LOG2E, -msc));
        float p3 = __builtin_amdgcn_exp2f(fmaf(sc[f][t][3], LOG2E, -msc));
        sc[f][t][0] = p0; sc[f][t][1] = p1; sc[f][t][2] = p2; sc[f][t][3] = p3;
        rsp[t] = (p0 + p1) + (p2 + p3);
      }
      float rs = (rsp[0] + rsp[1]) + (rsp[2] + rsp[3]);
      rs = redsum_q(rs);
      lrun[f] = lrun[f] * alpha + rs;
      #pragma unroll
      for (int t = 0; t < 4; ++t) {
        uint2 pw;
        pw.x = (unsigned int)f2bf(sc[f][t][0]) | ((unsigned int)f2bf(sc[f][t][1]) << 16);
        pw.y = (unsigned int)f2bf(sc[f][t][2]) | ((unsigned int)f2bf(sc[f][t][3]) << 16);
        *(uint2*)&Plds[wave][f][l15 * LDK + 16 * t + 4 * quad] = pw;
      }
      #pragma unroll
      for (int t = 0; t < 4; ++t)
        #pragma unroll
        for (int r = 0; r < 4; ++r) ot[f][t][r] *= alpha;
    }

    // ---- O^T += V^T * P^T; V fragment read once, used for both frags
    __builtin_amdgcn_s_setprio(1);
    #pragma unroll
    for (int s2 = 0; s2 < 2; ++s2) {
      bf16x8 pb0, pb1;
      if (f0act) pb0 = *(const bf16x8*)&Plds[wave][0][l15 * LDK + 32 * s2 + quad * 8];
      pb1 = *(const bf16x8*)&Plds[wave][1][l15 * LDK + 32 * s2 + quad * 8];
      #pragma unroll
      for (int t = 0; t < 4; ++t) {
        const int d = 16 * t + l15;
        bf16x8 va = *(const bf16x8*)&Vb[vrow(d) * LDK + (((4 * s2 + quad) ^ vswz_m(d)) << 3)];
        if (f0act)
          ot[0][t] = __builtin_amdgcn_mfma_f32_16x16x32_bf16(va, pb0, ot[0][t], 0, 0, 0);
        ot[1][t] = __builtin_amdgcn_mfma_f32_16x16x32_bf16(va, pb1, ot[1][t], 0, 0, 0);
      }
    }
    __builtin_amdgcn_s_setprio(0);
  }

  // ---- epilogue
  #pragma unroll
  for (int f = 0; f < 2; ++f) {
    float inv = 1.0f / lrun[f];
    float* orow = out + base + (qbase + 64 * f + wave * 16 + l15) * Ddim + 4 * quad;
    #pragma unroll
    for (int t = 0; t < 4; ++t) {
      f32x4 o4;
      o4.x = ot[f][t][0] * inv; o4.y = ot[f][t][1] * inv;
      o4.z = ot[f][t][2] * inv; o4.w = ot[f][t][3] * inv;
      *(f32x4*)(orow + 16 * t) = o4;
    }
  }

  // ---- zero-fill placeholder, share inverse to compute (fill-rank gp).
  {
    const int gp = (STiles - 1) - s;             // 0 = heaviest compute
    const int w  = 2 * gp + 1;
    const size_t start_f4 = (size_t)bh * FILL_PER_BH + (size_t)4096 * (gp * gp);
    const size_t count_f4 = (size_t)4096 * w;
    f32x4 z4 = (f32x4){0.f, 0.f, 0.f, 0.f};
    f32x4* zp = (f32x4*)(out + OUT0) + start_f4;
    for (size_t i = tid; i < count_f4; i += 256)
      __builtin_nontemporal_store(z4, zp + i);
  }
}

extern "C" void kernel_launch(void* const* d_in, const int* in_sizes, int n_in,
                              void* d_out, int out_size, void* d_ws, size_t ws_size,
                              hipStream_t stream) {
  const float* q = (const float*)d_in[0];
  const float* k = (const float*)d_in[1];
  const float* v = (const float*)d_in[2];
  float* out = (float*)d_out;
  dim3 grid(BHn * STiles);   // 512 blocks: 32 bh x 16 supertiles, all co-resident
  flash_causal_kernel<<<grid, dim3(256), 0, stream>>>(q, k, v, out);
}